// Round 11
// baseline (498.591 us; speedup 1.0000x reference)
//
#include <hip/hip_runtime.h>

#define NB 16
#define NA 261888
#define PRE 6000
#define POST 1000
#define CAP 8192
#define SEG 256
#define NSEG ((PRE + SEG - 1) / SEG)   // 24
#define KPAD 1024
#define THRF 0.972f
// Exact NMS predicate: RN32(inter/denom) > 0.7f  <=>  inter >= M*denom with
// M = midpoint(0.7f, nextafterf) = 0x1.666667p-1 (25-bit mantissa).
// f32-only form: fmaf(0.7f, denom, -inter) <= -2^-25*denom. Exact because
// M*denom - inter lies on a lattice of spacing 2^(ed-48) while the RN hazard
// band around -T is 2^(ed-49); equality (e==-T) included on both sides.

typedef unsigned int u32;
typedef unsigned long long u64;

__device__ __constant__ int NE_UNITS[10] = {0, 1, 2, 3, 5, 6, 7, 10, 11, 15};

__device__ inline float box_area(float4 v) {
    return __fmul_rn(__fadd_rn(__fsub_rn(v.z, v.x), 1.0f),
                     __fadd_rn(__fsub_rn(v.w, v.y), 1.0f));
}

__device__ inline bool iou_supp(float4 a, float aa, float4 c, float ca) {
    float xx1 = fmaxf(c.x, a.x);
    float yy1 = fmaxf(c.y, a.y);
    float xx2 = fminf(c.z, a.z);
    float yy2 = fminf(c.w, a.w);
    float iw = fmaxf(__fadd_rn(__fsub_rn(xx2, xx1), 1.0f), 0.f);
    float ih = fmaxf(__fadd_rn(__fsub_rn(yy2, yy1), 1.0f), 0.f);
    float inter = __fmul_rn(iw, ih);
    float denom = __fsub_rn(__fadd_rn(ca, aa), inter);
    return __fmaf_rn(0.7f, denom, -inter) <= __fmul_rn(denom, -0x1p-25f);
}

// ---------------- anchors (match numpy float64 -> float32 exactly) -------------
__device__ inline void anchor_at(int idx, float& a0, float& a1, float& a2, float& a3) {
    int base, fw, stride, scale;
    if (idx < 196608)      { base = 0;      fw = 256; stride = 4;  scale = 4; }
    else if (idx < 245760) { base = 196608; fw = 128; stride = 8;  scale = 8; }
    else if (idx < 258048) { base = 245760; fw = 64;  stride = 16; scale = 16; }
    else if (idx < 261120) { base = 258048; fw = 32;  stride = 32; scale = 32; }
    else                   { base = 261120; fw = 16;  stride = 64; scale = 64; }
    int rel  = idx - base;
    int ri   = rel % 3;
    int cell = rel / 3;
    int col  = cell & (fw - 1);
    int row  = cell / fw;
    double cx = (col + 0.5) * (double)stride;
    double cy = (row + 0.5) * (double)stride;
    double sz = (double)scale * 8.0;
    double sq = (ri == 0) ? 0.7071067811865476 : ((ri == 1) ? 1.0 : 1.4142135623730951);
    double wsd = sz * sq;
    double hsd = sz / sq;
    a0 = (float)(cx - 0.5 * wsd);
    a1 = (float)(cy - 0.5 * hsd);
    a2 = (float)(cx + 0.5 * wsd);
    a3 = (float)(cy + 0.5 * hsd);
}

__device__ inline float4 decode_box(u64 key, int b, const float* __restrict__ deltas,
                                    float hmax, float wmax) {
    int a = (int)(~(u32)key);
    float a0, a1, a2, a3;
    anchor_at(a, a0, a1, a2, a3);
    const float4 d4 = *(const float4*)(deltas + ((size_t)b * NA + a) * 4);
    float w  = __fadd_rn(__fsub_rn(a2, a0), 1.0f);
    float h  = __fadd_rn(__fsub_rn(a3, a1), 1.0f);
    float cx = __fadd_rn(a0, __fmul_rn(0.5f, w));
    float cy = __fadd_rn(a1, __fmul_rn(0.5f, h));
    float pcx = __fadd_rn(__fmul_rn(d4.x, w), cx);
    float pcy = __fadd_rn(__fmul_rn(d4.y, h), cy);
    float pw  = __fmul_rn((float)exp((double)d4.z), w);
    float ph  = __fmul_rn((float)exp((double)d4.w), h);
    float x1 = __fsub_rn(pcx, __fmul_rn(0.5f, pw));
    float y1 = __fsub_rn(pcy, __fmul_rn(0.5f, ph));
    float x2 = __fadd_rn(pcx, __fmul_rn(0.5f, pw));
    float y2 = __fadd_rn(pcy, __fmul_rn(0.5f, ph));
    x1 = fminf(fmaxf(x1, 0.f), wmax);
    x2 = fminf(fmaxf(x2, 0.f), wmax);
    y1 = fminf(fmaxf(y1, 0.f), hmax);
    y2 = fminf(fmaxf(y2, 0.f), hmax);
    return make_float4(x1, y1, x2, y2);
}

// ---------------- fast path: fixed-threshold compact, block-aggregated ---------
__global__ void compact_fixed(const float* __restrict__ probs, u32* __restrict__ cntp,
                              u64* __restrict__ cand) {
    __shared__ u32 lcnt;
    __shared__ u32 lbase;
    int tid = threadIdx.x;
    int a = blockIdx.x * 256 + tid;
    int b = blockIdx.y;
    if (tid == 0) lcnt = 0;
    __syncthreads();
    float2 pv = *(const float2*)(probs + ((size_t)b * NA + a) * 2);
    float s = pv.y;
    u32 bits = __float_as_uint(s);
    int lpos = -1;
    if (s >= THRF) lpos = (int)atomicAdd(&lcnt, 1u);
    __syncthreads();
    if (tid == 0) lbase = lcnt ? atomicAdd(&cntp[b * 64], lcnt) : 0u;
    __syncthreads();
    if (lpos >= 0) {
        u32 pos = lbase + (u32)lpos;
        if (pos < CAP)
            cand[(size_t)b * CAP + pos] = ((u64)bits << 32) | (u32)(~(u32)a);
    }
}

// ---------------- validate fast path; set per-batch fallback flags -------------
__global__ void check_kernel(u32* __restrict__ cntp, u32* __restrict__ flag) {
    int t = threadIdx.x;
    if (t < NB) {
        u32 c = cntp[t * 64];
        u32 bad = (c < (u32)PRE || c > (u32)CAP) ? 1u : 0u;
        flag[t * 64] = bad;
        if (bad) cntp[t * 64] = 0;
    }
}

// ---------------- gated fallback: zero hist ------------------------------------
__global__ void zero_hist(const u32* __restrict__ flag, u32* __restrict__ hist) {
    int b = blockIdx.y;
    if (flag[b * 64] == 0) return;
    int i = blockIdx.x * 256 + threadIdx.x;
    hist[(size_t)b * 65536 + i] = 0;
}

// ---------------- gated fallback: histogram ------------------------------------
__global__ void hist_kernel(const u32* __restrict__ flag, const float* __restrict__ probs,
                            u32* __restrict__ hist) {
    int b = blockIdx.y;
    if (flag[b * 64] == 0) return;
    int a = blockIdx.x * 256 + threadIdx.x;
    float2 pv = *(const float2*)(probs + ((size_t)b * NA + a) * 2);
    u32 bits = __float_as_uint(pv.y);
    atomicAdd(&hist[(size_t)b * 65536 + (bits >> 16)], 1u);
}

// ---------------- gated fallback: per-batch threshold --------------------------
__global__ __launch_bounds__(1024) void thresh_kernel(const u32* __restrict__ flag,
                                                      const u32* __restrict__ hist,
                                                      u32* __restrict__ thr) {
    int b = blockIdx.x;
    if (flag[b * 64] == 0) return;
    __shared__ u32 csum[1024];
    int t = threadIdx.x;
    const u32* h = hist + (size_t)b * 65536;
    u32 s = 0;
    for (int k = 0; k < 64; k++) s += h[t * 64 + k];
    csum[t] = s;
    __syncthreads();
    if (t == 0) {
        u32 cum = 0;
        int bucket = 0;
        for (int c = 1023; c >= 0; c--) {
            if (cum + csum[c] >= (u32)PRE) {
                u32 cum2 = cum;
                for (int k = 63; k >= 0; k--) {
                    cum2 += h[c * 64 + k];
                    if (cum2 >= (u32)PRE) { bucket = c * 64 + k; break; }
                }
                break;
            }
            cum += csum[c];
        }
        thr[b] = (u32)bucket << 16;
    }
}

// ---------------- gated fallback: compact with exact threshold -----------------
__global__ void compact2_kernel(const u32* __restrict__ flag, const float* __restrict__ probs,
                                const u32* __restrict__ thr, u32* __restrict__ cntp,
                                u64* __restrict__ cand) {
    int b = blockIdx.y;
    if (flag[b * 64] == 0) return;
    __shared__ u32 lcnt;
    __shared__ u32 lbase;
    int tid = threadIdx.x;
    int a = blockIdx.x * 256 + tid;
    if (tid == 0) lcnt = 0;
    __syncthreads();
    float2 pv = *(const float2*)(probs + ((size_t)b * NA + a) * 2);
    u32 bits = __float_as_uint(pv.y);
    int lpos = -1;
    if (bits >= thr[b]) lpos = (int)atomicAdd(&lcnt, 1u);
    __syncthreads();
    if (tid == 0) lbase = lcnt ? atomicAdd(&cntp[b * 64], lcnt) : 0u;
    __syncthreads();
    if (lpos >= 0) {
        u32 pos = lbase + (u32)lpos;
        if (pos < CAP)
            cand[(size_t)b * CAP + pos] = ((u64)bits << 32) | (u32)(~(u32)a);
    }
}

// ---------------- per-batch bitonic sort of candidate keys ---------------------
__global__ __launch_bounds__(1024) void sort_kernel(u64* __restrict__ cand, const u32* __restrict__ cntp) {
    __shared__ u64 keys[CAP];
    int b = blockIdx.x, tid = threadIdx.x;
    int n = (int)min(cntp[b * 64], (u32)CAP);
    u64* cb = cand + (size_t)b * CAP;
    for (int i = tid; i < CAP; i += 1024) keys[i] = (i < n) ? cb[i] : 0ULL;
    __syncthreads();
    for (int k = 2; k <= CAP; k <<= 1) {
        for (int j = k >> 1; j > 0; j >>= 1) {
            for (int i = tid; i < CAP; i += 1024) {
                int ixj = i ^ j;
                if (ixj > i) {
                    u64 x = keys[i], y = keys[ixj];
                    bool desc = ((i & k) == 0);
                    if (desc ? (x < y) : (x > y)) { keys[i] = y; keys[ixj] = x; }
                }
            }
            __syncthreads();
        }
    }
    for (int i = tid; i < PRE; i += 1024) cb[i] = keys[i];
}

// ---------------- pipelined fused lazy NMS (size-class binned phase A) ---------
// One block/batch, 1024 threads, double-buffered 256-row segments.
// Rows of segment s+1 are counting-sorted by (sizeclass<<6)|morton6 so that
// phase-A waves hold spatially tight 16-row groups; per-kept reject tests the
// 16-row group bbox (wave-uniform all-groups-reject -> skip IoU entirely).
__global__ __launch_bounds__(1024) void nms_fused(const u64* __restrict__ cand,
                                                  const float* __restrict__ deltas,
                                                  const float* __restrict__ img_info,
                                                  float* __restrict__ out) {
    __shared__ float4 segBox[2][SEG];
    __shared__ float  segArea[2][SEG];
    __shared__ u32    tile[2][SEG][8];
    __shared__ u32    aliveW[2][8];
    __shared__ unsigned char aliveB[4][SEG];
    __shared__ float4 keptBox[KPAD];
    __shared__ float  keptArea[KPAD];
    __shared__ unsigned char keyB[SEG];
    __shared__ short  rankB[SEG];
    __shared__ short  perm[SEG];
    __shared__ u32    binCnt[256];
    __shared__ u32    binOff[256];
    __shared__ u32    waveSum[4];
    __shared__ int    Kvar;

    int b = blockIdx.x;
    int t = threadIdx.x;
    int lane = t & 63;
    int w = t >> 6;
    if (t == 0) Kvar = 0;
    float hmax = __fsub_rn(img_info[b * 3 + 0], 1.0f);
    float wmax = __fsub_rn(img_info[b * 3 + 1], 1.0f);

    // ---- prolog: decode segment 0 + its tile + aliveW + identity perm
    if (t < SEG) {
        u64 key = cand[(size_t)b * CAP + t];
        float4 bx = decode_box(key, b, deltas, hmax, wmax);
        segBox[0][t] = bx;
        segArea[0][t] = box_area(bx);
        perm[t] = (short)t;
    }
    __syncthreads();
    if (w < 10) {
        int u = NE_UNITS[w];
        int wc = u & 3, h = u >> 2;
        int c = wc * 64 + lane;
        float4 cb = segBox[0][c];
        float  ca = segArea[0][c];
        for (int r = h * 64; r < h * 64 + 64; ++r) {
            float4 rb = segBox[0][r];
            float  ra = segArea[0][r];
            bool bit = (r < c) && iou_supp(rb, ra, cb, ca);
            u64 bal = __ballot(bit);
            if (lane == 0) tile[0][r][2 * wc]     = (u32)bal;
            if (lane == 1) tile[0][r][2 * wc + 1] = (u32)(bal >> 32);
        }
    }
    if (t < SEG) {
        u64 bal = __ballot(true);
        if (lane == 0) aliveW[0][2 * w]     = (u32)bal;
        if (lane == 1) aliveW[0][2 * w + 1] = (u32)(bal >> 32);
    }

    int Kprev = 0;
    for (int s = 0; s < NSEG; ++s) {
        int bufc = s & 1, bufn = bufc ^ 1;
        __syncthreads();                       // barrier A
        int Kcur = Kvar;
        if (Kcur >= POST) break;               // uniform

        // ---- R1: phase3(bufc) + decode(bufn) + sort key; waves 12-15 zero bins
        if (t < SEG) {
            if (s > 0) {
                bool al = aliveB[0][t] && aliveB[1][t] && aliveB[2][t] && aliveB[3][t];
                if (al && Kcur > Kprev) {
                    float4 rb = segBox[bufc][t];
                    float  ra = segArea[bufc][t];
                    int k = Kprev;
                    while (k < Kcur) {
                        bool d0 = iou_supp(keptBox[k], keptArea[k], rb, ra);
                        bool d1 = ((k + 1) < Kcur) & iou_supp(keptBox[k + 1], keptArea[k + 1], rb, ra);
                        bool d2 = ((k + 2) < Kcur) & iou_supp(keptBox[k + 2], keptArea[k + 2], rb, ra);
                        bool d3 = ((k + 3) < Kcur) & iou_supp(keptBox[k + 3], keptArea[k + 3], rb, ra);
                        if (d0 | d1 | d2 | d3) { al = false; break; }
                        k += 4;
                    }
                }
                u64 bal = __ballot(al);
                if (lane == 0) aliveW[bufc][2 * w]     = (u32)bal;
                if (lane == 1) aliveW[bufc][2 * w + 1] = (u32)(bal >> 32);
            }
            if (s + 1 < NSEG) {
                int g = (s + 1) * SEG + t;
                float4 bx = make_float4(0.f, 0.f, 0.f, 0.f);
                float ar = 0.f;
                bool valid = (g < PRE);
                if (valid) {
                    u64 key = cand[(size_t)b * CAP + g];
                    bx = decode_box(key, b, deltas, hmax, wmax);
                    ar = box_area(bx);
                }
                segBox[bufn][t] = bx;
                segArea[bufn][t] = ar;
                unsigned char v8 = valid ? 1 : 0;
                aliveB[0][t] = v8; aliveB[1][t] = v8; aliveB[2][t] = v8; aliveB[3][t] = v8;
                float szw = __fsub_rn(bx.z, bx.x);
                int cls = (szw > 96.f) ? ((szw > 256.f) ? 2 : 1) : 0;
                int bxq = (int)bx.x >> 7; bxq = (bxq < 0) ? 0 : ((bxq > 7) ? 7 : bxq);
                int byq = (int)bx.y >> 7; byq = (byq < 0) ? 0 : ((byq > 7) ? 7 : byq);
                int m6 = (bxq & 1) | ((byq & 1) << 1) | ((bxq & 2) << 1) |
                         ((byq & 2) << 2) | ((bxq & 4) << 2) | ((byq & 4) << 3);
                keyB[t] = (unsigned char)((cls << 6) | m6);
            }
        } else if (t >= 768) {
            binCnt[t - 768] = 0;
        }
        __syncthreads();                       // barrier A2
        if (t < SEG && s + 1 < NSEG)
            rankB[t] = (short)atomicAdd(&binCnt[keyB[t]], 1u);
        __syncthreads();                       // barrier A3
        u32 scn_c = 0, scn_x = 0;
        if (t < 256) {
            scn_c = binCnt[t];
            scn_x = scn_c;
            for (int off = 1; off < 64; off <<= 1) {
                u32 y = __shfl_up(scn_x, off);
                if (lane >= off) scn_x += y;
            }
            if (lane == 63) waveSum[w] = scn_x;
        }
        __syncthreads();                       // barrier A3b
        if (t < 256) {
            u32 add = 0;
            if (w > 0) add += waveSum[0];
            if (w > 1) add += waveSum[1];
            if (w > 2) add += waveSum[2];
            binOff[t] = scn_x - scn_c + add;
        }
        __syncthreads();                       // barrier A4
        if (t < SEG && s + 1 < NSEG)
            perm[binOff[keyB[t]] + rankB[t]] = (short)t;
        __syncthreads();                       // barrier B

        if (w == 0) {
            // ---- serial greedy scan of segment s (wave 0)
            int l = lane;
            u32 va = (l < 8) ? aliveW[bufc][l] : 0u;
            int KK = Kcur;
            while (true) {
                u64 balv = __ballot(va != 0u);
                if (balv == 0ULL) break;
                int wsel = __ffsll(balv) - 1;
                u32 word = __builtin_amdgcn_readlane(va, wsel);
                int r = (wsel << 5) + (__ffs(word) - 1);
                u32 trow = tile[bufc][r][l & 7];
                if (l >= 8 && l < 12)
                    ((float*)keptBox)[KK * 4 + (l - 8)] = ((const float*)segBox[bufc])[r * 4 + (l - 8)];
                if (l == 12) keptArea[KK] = segArea[bufc][r];
                u32 self = (l == (r >> 5)) ? (1u << (r & 31)) : 0u;
                if (l < 8) va &= ~(trow | self);
                ++KK;
                if (KK == POST) break;
            }
            if (l == 0) Kvar = KK;
        } else {
            int ww = w - 1;                    // 0..14
            if (s + 1 < NSEG && Kcur > 0) {
                // ---- phase A on sorted rows, 16-row group-bbox rejects
                int rg, kc, kstep;
                if (ww < 12) { rg = ww >> 2; kc = ww & 3; kstep = 4; }
                else         { rg = 3;       kc = ww - 12; kstep = 3; }
                int row = (int)perm[rg * 64 + lane];
                float4 rb = segBox[bufn][row];
                float  ra = segArea[bufn][row];
                float gx1 = rb.x, gy1 = rb.y, gx2 = rb.z, gy2 = rb.w;
                for (int off = 1; off < 16; off <<= 1) {
                    gx1 = fminf(gx1, __shfl_xor(gx1, off, 16));
                    gy1 = fminf(gy1, __shfl_xor(gy1, off, 16));
                    gx2 = fmaxf(gx2, __shfl_xor(gx2, off, 16));
                    gy2 = fmaxf(gy2, __shfl_xor(gy2, off, 16));
                }
                bool dead = false, written = false;
                int q = 0;
                for (int k = kc; k < Kcur; k += kstep) {
                    float4 kb = keptBox[k];
                    bool ov = !((__fadd_rn(kb.z, 1.f) <= gx1) | (__fadd_rn(gx2, 1.f) <= kb.x) |
                                (__fadd_rn(kb.w, 1.f) <= gy1) | (__fadd_rn(gy2, 1.f) <= kb.y));
                    if (__ballot(ov)) {
                        dead |= iou_supp(kb, keptArea[k], rb, ra);
                    }
                    if (((++q) & 15) == 0) {
                        if (dead && !written) { aliveB[kc][row] = 0; written = true; }
                        u32 comb = (u32)aliveB[0][row] & (u32)aliveB[1][row] &
                                   (u32)aliveB[2][row] & (u32)aliveB[3][row];
                        if (__ballot(comb != 0u) == 0ULL) break;
                    }
                }
                if (dead && !written) aliveB[kc][row] = 0;
            }
            // ---- intra-segment tile build for s+1 (waves 1..10, one unit each)
            if (s + 1 < NSEG && ww < 10) {
                int u = NE_UNITS[ww];
                int wc = u & 3, h = u >> 2;
                int c = wc * 64 + lane;
                float4 cb = segBox[bufn][c];
                float  ca = segArea[bufn][c];
                for (int r = h * 64; r < h * 64 + 64; ++r) {
                    float4 rb = segBox[bufn][r];
                    float  ra = segArea[bufn][r];
                    bool bit = (r < c) && iou_supp(rb, ra, cb, ca);
                    u64 bal = __ballot(bit);
                    if (lane == 0) tile[bufn][r][2 * wc]     = (u32)bal;
                    if (lane == 1) tile[bufn][r][2 * wc + 1] = (u32)(bal >> 32);
                }
            }
        }
        Kprev = Kcur;
    }
    __syncthreads();

    // ---- epilogue: write output
    int K = Kvar;
    for (int s2 = t; s2 < POST; s2 += 1024) {
        float* o = out + ((size_t)b * POST + s2) * 5;
        if (s2 < K) {
            float4 bx = keptBox[s2];
            o[0] = (float)b; o[1] = bx.x; o[2] = bx.y; o[3] = bx.z; o[4] = bx.w;
        } else {
            o[0] = (float)b; o[1] = 0.f; o[2] = 0.f; o[3] = 0.f; o[4] = 0.f;
        }
    }
}

// ---------------- fallback: monolithic sort+decode+NMS (small ws) --------------
__global__ __launch_bounds__(1024) void final_kernel(const u64* __restrict__ cand, const u32* __restrict__ cntp,
                             const float* __restrict__ deltas, const float* __restrict__ img_info,
                             float* __restrict__ out) {
    __shared__ union {
        u64 keys[CAP];
        struct {
            float boxes[PRE][4];
            float areas[PRE];
            u32   alive[192];
        } n;
    } sh;
    __shared__ int s_next;

    int b = blockIdx.x;
    int tid = threadIdx.x;

    for (int s = tid; s < POST; s += 1024) {
        float* o = out + ((size_t)b * POST + s) * 5;
        o[0] = (float)b; o[1] = 0.f; o[2] = 0.f; o[3] = 0.f; o[4] = 0.f;
    }

    int n = (int)min(cntp[b * 64], (u32)CAP);
    for (int i = tid; i < CAP; i += 1024)
        sh.keys[i] = (i < n) ? cand[(size_t)b * CAP + i] : 0ULL;
    __syncthreads();

    for (int k = 2; k <= CAP; k <<= 1) {
        for (int j = k >> 1; j > 0; j >>= 1) {
            for (int i = tid; i < CAP; i += 1024) {
                int ixj = i ^ j;
                if (ixj > i) {
                    u64 x = sh.keys[i], y = sh.keys[ixj];
                    bool desc = ((i & k) == 0);
                    if (desc ? (x < y) : (x > y)) { sh.keys[i] = y; sh.keys[ixj] = x; }
                }
            }
            __syncthreads();
        }
    }

    u32 myIdx[6];
    #pragma unroll
    for (int r = 0; r < 6; r++) {
        int i = tid + r * 1024;
        if (i < PRE) myIdx[r] = ~(u32)(sh.keys[i]);
    }
    __syncthreads();

    float hmax = __fsub_rn(img_info[b * 3 + 0], 1.0f);
    float wmax = __fsub_rn(img_info[b * 3 + 1], 1.0f);

    #pragma unroll
    for (int r = 0; r < 6; r++) {
        int i = tid + r * 1024;
        if (i < PRE) {
            int a = (int)myIdx[r];
            float a0, a1, a2, a3;
            anchor_at(a, a0, a1, a2, a3);
            const float4 d4 = *(const float4*)(deltas + ((size_t)b * NA + a) * 4);
            float w  = __fadd_rn(__fsub_rn(a2, a0), 1.0f);
            float h  = __fadd_rn(__fsub_rn(a3, a1), 1.0f);
            float cx = __fadd_rn(a0, __fmul_rn(0.5f, w));
            float cy = __fadd_rn(a1, __fmul_rn(0.5f, h));
            float pcx = __fadd_rn(__fmul_rn(d4.x, w), cx);
            float pcy = __fadd_rn(__fmul_rn(d4.y, h), cy);
            float pw  = __fmul_rn((float)exp((double)d4.z), w);
            float ph  = __fmul_rn((float)exp((double)d4.w), h);
            float x1 = __fsub_rn(pcx, __fmul_rn(0.5f, pw));
            float y1 = __fsub_rn(pcy, __fmul_rn(0.5f, ph));
            float x2 = __fadd_rn(pcx, __fmul_rn(0.5f, pw));
            float y2 = __fadd_rn(pcy, __fmul_rn(0.5f, ph));
            x1 = fminf(fmaxf(x1, 0.f), wmax);
            x2 = fminf(fmaxf(x2, 0.f), wmax);
            y1 = fminf(fmaxf(y1, 0.f), hmax);
            y2 = fminf(fmaxf(y2, 0.f), hmax);
            sh.n.boxes[i][0] = x1; sh.n.boxes[i][1] = y1;
            sh.n.boxes[i][2] = x2; sh.n.boxes[i][3] = y2;
            sh.n.areas[i] = __fmul_rn(__fadd_rn(__fsub_rn(x2, x1), 1.0f),
                                      __fadd_rn(__fsub_rn(y2, y1), 1.0f));
        }
    }

    for (int wdi = tid; wdi < 192; wdi += 1024) {
        u32 v = 0xFFFFFFFFu;
        if (wdi == 187) v = 0x0000FFFFu;
        if (wdi > 187)  v = 0u;
        sh.n.alive[wdi] = v;
    }
    __syncthreads();

    int kept = 0;
    int scanWord = 0;
    while (kept < POST) {
        if (tid == 0) {
            int found = -1;
            while (scanWord < 188) {
                u32 wv = sh.n.alive[scanWord];
                if (wv) { found = scanWord * 32 + (__ffs(wv) - 1); break; }
                scanWord++;
            }
            s_next = found;
        }
        __syncthreads();
        int i = s_next;
        if (i < 0) break;
        float bx1 = sh.n.boxes[i][0], by1 = sh.n.boxes[i][1];
        float bx2 = sh.n.boxes[i][2], by2 = sh.n.boxes[i][3];
        float bar = sh.n.areas[i];
        if (tid == 0) {
            float* o = out + ((size_t)b * POST + kept) * 5;
            o[1] = bx1; o[2] = by1; o[3] = bx2; o[4] = by2;
            atomicAnd(&sh.n.alive[i >> 5], ~(1u << (i & 31)));
        }
        for (int j = i + 1 + tid; j < PRE; j += 1024) {
            float x1 = sh.n.boxes[j][0], y1 = sh.n.boxes[j][1];
            float x2 = sh.n.boxes[j][2], y2 = sh.n.boxes[j][3];
            float xx1 = fmaxf(x1, bx1), yy1 = fmaxf(y1, by1);
            float xx2 = fminf(x2, bx2), yy2 = fminf(y2, by2);
            float iw = fmaxf(__fadd_rn(__fsub_rn(xx2, xx1), 1.0f), 0.f);
            float ih = fmaxf(__fadd_rn(__fsub_rn(yy2, yy1), 1.0f), 0.f);
            float inter = __fmul_rn(iw, ih);
            float denom = __fsub_rn(__fadd_rn(sh.n.areas[j], bar), inter);
            float iou = __fdiv_rn(inter, denom);
            if (iou > 0.7f) atomicAnd(&sh.n.alive[j >> 5], ~(1u << (j & 31)));
        }
        kept++;
        __syncthreads();
    }
}

// ---------------- launcher -----------------------------------------------------
extern "C" void kernel_launch(void* const* d_in, const int* in_sizes, int n_in,
                              void* d_out, int out_size, void* d_ws, size_t ws_size,
                              hipStream_t stream) {
    const float* probs    = (const float*)d_in[0];
    const float* deltas   = (const float*)d_in[1];
    const float* img_info = (const float*)d_in[2];
    float* out = (float*)d_out;

    char* ws = (char*)d_ws;
    size_t off = 0;
    u32* cntp = (u32*)(ws + off); off += (size_t)NB * 64 * sizeof(u32);
    u32* flag = (u32*)(ws + off); off += (size_t)NB * 64 * sizeof(u32);
    u32* thr  = (u32*)(ws + off); off += 4096;
    u32* hist = (u32*)(ws + off); off += (size_t)NB * 65536 * sizeof(u32);
    u64* cand = (u64*)(ws + off); off += (size_t)NB * CAP * sizeof(u64);
    bool bigws = (ws_size >= off);

    dim3 gA((NA + 255) / 256, NB);

    hipMemsetAsync(cntp, 0, (size_t)NB * 64 * sizeof(u32), stream);

    if (bigws) {
        compact_fixed<<<gA, 256, 0, stream>>>(probs, cntp, cand);
        check_kernel<<<1, 64, 0, stream>>>(cntp, flag);
        zero_hist<<<dim3(256, NB), 256, 0, stream>>>(flag, hist);
        hist_kernel<<<gA, 256, 0, stream>>>(flag, probs, hist);
        thresh_kernel<<<NB, 1024, 0, stream>>>(flag, hist, thr);
        compact2_kernel<<<gA, 256, 0, stream>>>(flag, probs, thr, cntp, cand);
        sort_kernel<<<NB, 1024, 0, stream>>>(cand, cntp);
        nms_fused<<<NB, 1024, 0, stream>>>(cand, deltas, img_info, out);
    } else {
        hipMemsetAsync(flag, 1, (size_t)NB * 64 * sizeof(u32), stream);
        hipMemsetAsync(hist, 0, (size_t)NB * 65536 * sizeof(u32), stream);
        hist_kernel<<<gA, 256, 0, stream>>>(flag, probs, hist);
        thresh_kernel<<<NB, 1024, 0, stream>>>(flag, hist, thr);
        compact2_kernel<<<gA, 256, 0, stream>>>(flag, probs, thr, cntp, cand);
        final_kernel<<<NB, 1024, 0, stream>>>(cand, cntp, deltas, img_info, out);
    }
}

// Round 12
// 497.209 us; speedup vs baseline: 1.0028x; 1.0028x over previous
//
#include <hip/hip_runtime.h>

#define NB 16
#define NA 261888
#define PRE 6000
#define POST 1000
#define CAP 8192
#define SEG 256
#define NSEG ((PRE + SEG - 1) / SEG)   // 24
#define BOXSTRIDE 6144
#define KPAD 1024
#define THRF 0.972f
// Exact NMS predicate: RN32(inter/denom) > 0.7f  <=>  inter >= M*denom with
// M = midpoint(0.7f, nextafterf) = 0x1.666667p-1 (25-bit mantissa).
// f32-only form: fmaf(0.7f, denom, -inter) <= -2^-25*denom. Exact because
// M*denom - inter lies on a lattice of spacing 2^(ed-48) while the RN hazard
// band around -T is 2^(ed-49); equality (e==-T) included on both sides.

typedef unsigned int u32;
typedef unsigned long long u64;

__device__ __constant__ int NE_UNITS[10] = {0, 1, 2, 3, 5, 6, 7, 10, 11, 15};
__device__ __constant__ int TILE_N[3] = {4, 3, 3};
__device__ __constant__ int TILE_U[3][4] = {{0, 5, 10, 15}, {1, 2, 6, 0}, {3, 7, 11, 0}};

__device__ inline float box_area(float4 v) {
    return __fmul_rn(__fadd_rn(__fsub_rn(v.z, v.x), 1.0f),
                     __fadd_rn(__fsub_rn(v.w, v.y), 1.0f));
}

__device__ inline bool iou_supp(float4 a, float aa, float4 c, float ca) {
    float xx1 = fmaxf(c.x, a.x);
    float yy1 = fmaxf(c.y, a.y);
    float xx2 = fminf(c.z, a.z);
    float yy2 = fminf(c.w, a.w);
    float iw = fmaxf(__fadd_rn(__fsub_rn(xx2, xx1), 1.0f), 0.f);
    float ih = fmaxf(__fadd_rn(__fsub_rn(yy2, yy1), 1.0f), 0.f);
    float inter = __fmul_rn(iw, ih);
    float denom = __fsub_rn(__fadd_rn(ca, aa), inter);
    return __fmaf_rn(0.7f, denom, -inter) <= __fmul_rn(denom, -0x1p-25f);
}

// ---------------- anchors (match numpy float64 -> float32 exactly) -------------
__device__ inline void anchor_at(int idx, float& a0, float& a1, float& a2, float& a3) {
    int base, fw, stride, scale;
    if (idx < 196608)      { base = 0;      fw = 256; stride = 4;  scale = 4; }
    else if (idx < 245760) { base = 196608; fw = 128; stride = 8;  scale = 8; }
    else if (idx < 258048) { base = 245760; fw = 64;  stride = 16; scale = 16; }
    else if (idx < 261120) { base = 258048; fw = 32;  stride = 32; scale = 32; }
    else                   { base = 261120; fw = 16;  stride = 64; scale = 64; }
    int rel  = idx - base;
    int ri   = rel % 3;
    int cell = rel / 3;
    int col  = cell & (fw - 1);
    int row  = cell / fw;
    double cx = (col + 0.5) * (double)stride;
    double cy = (row + 0.5) * (double)stride;
    double sz = (double)scale * 8.0;
    double sq = (ri == 0) ? 0.7071067811865476 : ((ri == 1) ? 1.0 : 1.4142135623730951);
    double wsd = sz * sq;
    double hsd = sz / sq;
    a0 = (float)(cx - 0.5 * wsd);
    a1 = (float)(cy - 0.5 * hsd);
    a2 = (float)(cx + 0.5 * wsd);
    a3 = (float)(cy + 0.5 * hsd);
}

__device__ inline float4 decode_box(u64 key, int b, const float* __restrict__ deltas,
                                    float hmax, float wmax) {
    int a = (int)(~(u32)key);
    float a0, a1, a2, a3;
    anchor_at(a, a0, a1, a2, a3);
    const float4 d4 = *(const float4*)(deltas + ((size_t)b * NA + a) * 4);
    float w  = __fadd_rn(__fsub_rn(a2, a0), 1.0f);
    float h  = __fadd_rn(__fsub_rn(a3, a1), 1.0f);
    float cx = __fadd_rn(a0, __fmul_rn(0.5f, w));
    float cy = __fadd_rn(a1, __fmul_rn(0.5f, h));
    float pcx = __fadd_rn(__fmul_rn(d4.x, w), cx);
    float pcy = __fadd_rn(__fmul_rn(d4.y, h), cy);
    float pw  = __fmul_rn((float)exp((double)d4.z), w);
    float ph  = __fmul_rn((float)exp((double)d4.w), h);
    float x1 = __fsub_rn(pcx, __fmul_rn(0.5f, pw));
    float y1 = __fsub_rn(pcy, __fmul_rn(0.5f, ph));
    float x2 = __fadd_rn(pcx, __fmul_rn(0.5f, pw));
    float y2 = __fadd_rn(pcy, __fmul_rn(0.5f, ph));
    x1 = fminf(fmaxf(x1, 0.f), wmax);
    x2 = fminf(fmaxf(x2, 0.f), wmax);
    y1 = fminf(fmaxf(y1, 0.f), hmax);
    y2 = fminf(fmaxf(y2, 0.f), hmax);
    return make_float4(x1, y1, x2, y2);
}

// ---------------- fast path: fixed-threshold compact, block-aggregated ---------
__global__ void compact_fixed(const float* __restrict__ probs, u32* __restrict__ cntp,
                              u64* __restrict__ cand) {
    __shared__ u32 lcnt;
    __shared__ u32 lbase;
    int tid = threadIdx.x;
    int a = blockIdx.x * 256 + tid;
    int b = blockIdx.y;
    if (tid == 0) lcnt = 0;
    __syncthreads();
    float2 pv = *(const float2*)(probs + ((size_t)b * NA + a) * 2);
    float s = pv.y;
    u32 bits = __float_as_uint(s);
    int lpos = -1;
    if (s >= THRF) lpos = (int)atomicAdd(&lcnt, 1u);
    __syncthreads();
    if (tid == 0) lbase = lcnt ? atomicAdd(&cntp[b * 64], lcnt) : 0u;
    __syncthreads();
    if (lpos >= 0) {
        u32 pos = lbase + (u32)lpos;
        if (pos < CAP)
            cand[(size_t)b * CAP + pos] = ((u64)bits << 32) | (u32)(~(u32)a);
    }
}

// ---------------- validate fast path; set per-batch fallback flags -------------
__global__ void check_kernel(u32* __restrict__ cntp, u32* __restrict__ flag) {
    int t = threadIdx.x;
    if (t < NB) {
        u32 c = cntp[t * 64];
        u32 bad = (c < (u32)PRE || c > (u32)CAP) ? 1u : 0u;
        flag[t * 64] = bad;
        if (bad) cntp[t * 64] = 0;
    }
}

// ---------------- gated fallback: zero hist ------------------------------------
__global__ void zero_hist(const u32* __restrict__ flag, u32* __restrict__ hist) {
    int b = blockIdx.y;
    if (flag[b * 64] == 0) return;
    int i = blockIdx.x * 256 + threadIdx.x;
    hist[(size_t)b * 65536 + i] = 0;
}

// ---------------- gated fallback: histogram ------------------------------------
__global__ void hist_kernel(const u32* __restrict__ flag, const float* __restrict__ probs,
                            u32* __restrict__ hist) {
    int b = blockIdx.y;
    if (flag[b * 64] == 0) return;
    int a = blockIdx.x * 256 + threadIdx.x;
    float2 pv = *(const float2*)(probs + ((size_t)b * NA + a) * 2);
    u32 bits = __float_as_uint(pv.y);
    atomicAdd(&hist[(size_t)b * 65536 + (bits >> 16)], 1u);
}

// ---------------- gated fallback: per-batch threshold --------------------------
__global__ __launch_bounds__(1024) void thresh_kernel(const u32* __restrict__ flag,
                                                      const u32* __restrict__ hist,
                                                      u32* __restrict__ thr) {
    int b = blockIdx.x;
    if (flag[b * 64] == 0) return;
    __shared__ u32 csum[1024];
    int t = threadIdx.x;
    const u32* h = hist + (size_t)b * 65536;
    u32 s = 0;
    for (int k = 0; k < 64; k++) s += h[t * 64 + k];
    csum[t] = s;
    __syncthreads();
    if (t == 0) {
        u32 cum = 0;
        int bucket = 0;
        for (int c = 1023; c >= 0; c--) {
            if (cum + csum[c] >= (u32)PRE) {
                u32 cum2 = cum;
                for (int k = 63; k >= 0; k--) {
                    cum2 += h[c * 64 + k];
                    if (cum2 >= (u32)PRE) { bucket = c * 64 + k; break; }
                }
                break;
            }
            cum += csum[c];
        }
        thr[b] = (u32)bucket << 16;
    }
}

// ---------------- gated fallback: compact with exact threshold -----------------
__global__ void compact2_kernel(const u32* __restrict__ flag, const float* __restrict__ probs,
                                const u32* __restrict__ thr, u32* __restrict__ cntp,
                                u64* __restrict__ cand) {
    int b = blockIdx.y;
    if (flag[b * 64] == 0) return;
    __shared__ u32 lcnt;
    __shared__ u32 lbase;
    int tid = threadIdx.x;
    int a = blockIdx.x * 256 + tid;
    if (tid == 0) lcnt = 0;
    __syncthreads();
    float2 pv = *(const float2*)(probs + ((size_t)b * NA + a) * 2);
    u32 bits = __float_as_uint(pv.y);
    int lpos = -1;
    if (bits >= thr[b]) lpos = (int)atomicAdd(&lcnt, 1u);
    __syncthreads();
    if (tid == 0) lbase = lcnt ? atomicAdd(&cntp[b * 64], lcnt) : 0u;
    __syncthreads();
    if (lpos >= 0) {
        u32 pos = lbase + (u32)lpos;
        if (pos < CAP)
            cand[(size_t)b * CAP + pos] = ((u64)bits << 32) | (u32)(~(u32)a);
    }
}

// ---------------- per-batch bitonic sort of candidate keys ---------------------
__global__ __launch_bounds__(1024) void sort_kernel(u64* __restrict__ cand, const u32* __restrict__ cntp) {
    __shared__ u64 keys[CAP];
    int b = blockIdx.x, tid = threadIdx.x;
    int n = (int)min(cntp[b * 64], (u32)CAP);
    u64* cb = cand + (size_t)b * CAP;
    for (int i = tid; i < CAP; i += 1024) keys[i] = (i < n) ? cb[i] : 0ULL;
    __syncthreads();
    for (int k = 2; k <= CAP; k <<= 1) {
        for (int j = k >> 1; j > 0; j >>= 1) {
            for (int i = tid; i < CAP; i += 1024) {
                int ixj = i ^ j;
                if (ixj > i) {
                    u64 x = keys[i], y = keys[ixj];
                    bool desc = ((i & k) == 0);
                    if (desc ? (x < y) : (x > y)) { keys[i] = y; keys[ixj] = x; }
                }
            }
            __syncthreads();
        }
    }
    for (int i = tid; i < PRE; i += 1024) cb[i] = keys[i];
}

// ---------------- decode all top-PRE boxes (fully parallel, all CUs) -----------
__global__ void decode_all(const u64* __restrict__ cand, const float* __restrict__ deltas,
                           const float* __restrict__ img_info, float4* __restrict__ gBoxes,
                           float* __restrict__ gAreas, float* __restrict__ out) {
    int s = blockIdx.x * 256 + threadIdx.x;     // 0..6143
    int b = blockIdx.y;
    if (s < POST) {
        float* o = out + ((size_t)b * POST + s) * 5;
        o[0] = (float)b; o[1] = 0.f; o[2] = 0.f; o[3] = 0.f; o[4] = 0.f;
    }
    float4 bx = make_float4(0.f, 0.f, 0.f, 0.f);
    float ar = 0.f;
    if (s < PRE) {
        float hmax = __fsub_rn(img_info[b * 3 + 0], 1.0f);
        float wmax = __fsub_rn(img_info[b * 3 + 1], 1.0f);
        u64 key = cand[(size_t)b * CAP + s];
        bx = decode_box(key, b, deltas, hmax, wmax);
        ar = box_area(bx);
    }
    gBoxes[(size_t)b * BOXSTRIDE + s] = bx;
    gAreas[(size_t)b * BOXSTRIDE + s] = ar;
}

// ---------------- pipelined fused lazy NMS (lean, decode hoisted out) ----------
// One block/batch, 1024 threads, double-buffered 256-row segments, 2 barriers
// per segment. Wave roles in the concurrent region:
//   wave 0     : serial greedy scan of seg s (tile + aliveW, appends kept)
//   waves 1-12 : phase A of seg s+1 vs kept[0..Kcur): rowgroup (w-1)&3,
//                keptchunk (w-1)>>2 (k = kc+3j, quad-unrolled)
//   waves 13-15: strict-upper intra-segment bit tile of seg s+1 (units 4/3/3)
__global__ __launch_bounds__(1024) void nms_fused(const float4* __restrict__ gBoxes,
                                                  const float* __restrict__ gAreas,
                                                  float* __restrict__ out) {
    __shared__ float4 segBox[2][SEG];
    __shared__ float  segArea[2][SEG];
    __shared__ u32    tile[2][SEG][8];
    __shared__ u32    aliveW[2][8];
    __shared__ unsigned char aliveB[3][SEG];
    __shared__ float4 keptBox[KPAD];
    __shared__ float  keptArea[KPAD];
    __shared__ int    Kvar;

    int b = blockIdx.x;
    int t = threadIdx.x;
    int lane = t & 63;
    int w = t >> 6;
    if (t == 0) Kvar = 0;
    const float4* gb = gBoxes + (size_t)b * BOXSTRIDE;
    const float*  ga = gAreas + (size_t)b * BOXSTRIDE;

    // ---- prolog: load segment 0 + its tile + aliveW
    if (t < SEG) {
        segBox[0][t] = gb[t];
        segArea[0][t] = ga[t];
    }
    __syncthreads();
    if (w < 10) {
        int u = NE_UNITS[w];
        int wc = u & 3, h = u >> 2;
        int c = wc * 64 + lane;
        float4 cb = segBox[0][c];
        float  ca = segArea[0][c];
        for (int r = h * 64; r < h * 64 + 64; ++r) {
            float4 rb = segBox[0][r];
            float  ra = segArea[0][r];
            bool bit = (r < c) && iou_supp(rb, ra, cb, ca);
            u64 bal = __ballot(bit);
            if (lane == 0) tile[0][r][2 * wc]     = (u32)bal;
            if (lane == 1) tile[0][r][2 * wc + 1] = (u32)(bal >> 32);
        }
    }
    if (t < SEG) {
        u64 bal = __ballot(true);
        if (lane == 0) aliveW[0][2 * w]     = (u32)bal;
        if (lane == 1) aliveW[0][2 * w + 1] = (u32)(bal >> 32);
    }

    int Kprev = 0;
    for (int s = 0; s < NSEG; ++s) {
        int bufc = s & 1, bufn = bufc ^ 1;
        __syncthreads();                       // barrier A
        int Kcur = Kvar;
        if (Kcur >= POST) break;               // uniform

        // ---- merged region (threads < 256): phase3(bufc) + load(bufn)
        if (t < SEG) {
            if (s > 0) {
                bool al = aliveB[0][t] && aliveB[1][t] && aliveB[2][t];
                if (al && Kcur > Kprev) {
                    float4 rb = segBox[bufc][t];
                    float  ra = segArea[bufc][t];
                    int k = Kprev;
                    while (k < Kcur) {
                        bool d0 = iou_supp(keptBox[k], keptArea[k], rb, ra);
                        bool d1 = ((k + 1) < Kcur) & iou_supp(keptBox[k + 1], keptArea[k + 1], rb, ra);
                        bool d2 = ((k + 2) < Kcur) & iou_supp(keptBox[k + 2], keptArea[k + 2], rb, ra);
                        bool d3 = ((k + 3) < Kcur) & iou_supp(keptBox[k + 3], keptArea[k + 3], rb, ra);
                        if (d0 | d1 | d2 | d3) { al = false; break; }
                        k += 4;
                    }
                }
                u64 bal = __ballot(al);
                if (lane == 0) aliveW[bufc][2 * w]     = (u32)bal;
                if (lane == 1) aliveW[bufc][2 * w + 1] = (u32)(bal >> 32);
            }
            if (s + 1 < NSEG) {
                int g = (s + 1) * SEG + t;
                segBox[bufn][t] = gb[g];
                segArea[bufn][t] = ga[g];
                unsigned char v8 = (g < PRE) ? 1 : 0;
                aliveB[0][t] = v8; aliveB[1][t] = v8; aliveB[2][t] = v8;
            }
        }
        __syncthreads();                       // barrier B

        if (w == 0) {
            // ---- serial greedy scan of segment s (wave 0)
            int l = lane;
            u32 va = (l < 8) ? aliveW[bufc][l] : 0u;
            int KK = Kcur;
            while (true) {
                u64 balv = __ballot(va != 0u);
                if (balv == 0ULL) break;
                int wsel = __ffsll(balv) - 1;
                u32 word = __builtin_amdgcn_readlane(va, wsel);
                int r = (wsel << 5) + (__ffs(word) - 1);
                u32 trow = tile[bufc][r][l & 7];
                if (l >= 8 && l < 12)
                    ((float*)keptBox)[KK * 4 + (l - 8)] = ((const float*)segBox[bufc])[r * 4 + (l - 8)];
                if (l == 12) keptArea[KK] = segArea[bufc][r];
                u32 self = (l == (r >> 5)) ? (1u << (r & 31)) : 0u;
                if (l < 8) va &= ~(trow | self);
                ++KK;
                if (KK == POST) break;
            }
            if (l == 0) Kvar = KK;
        } else if (w <= 12) {
            // ---- phase A of segment s+1 (waves 1-12)
            if (s + 1 < NSEG && Kcur > 0) {
                int ww = w - 1;
                int rg = ww & 3;
                int kc = ww >> 2;               // 0..2
                int row = rg * 64 + lane;
                float4 rb = segBox[bufn][row];
                float  ra = segArea[bufn][row];
                bool dead = false, written = false;
                int q = 0;
                int k = kc;
                while (k < Kcur) {
                    int k1 = k + 3, k2 = k + 6, k3 = k + 9;
                    bool d0 = iou_supp(keptBox[k], keptArea[k], rb, ra);
                    bool d1 = (k1 < Kcur) & iou_supp(keptBox[k1], keptArea[k1], rb, ra);
                    bool d2 = (k2 < Kcur) & iou_supp(keptBox[k2], keptArea[k2], rb, ra);
                    bool d3 = (k3 < Kcur) & iou_supp(keptBox[k3], keptArea[k3], rb, ra);
                    dead |= (d0 | d1 | d2 | d3);
                    k += 12;
                    if (((++q) & 7) == 0) {
                        if (dead && !written) { aliveB[kc][row] = 0; written = true; }
                        u32 comb = (u32)aliveB[0][row] & (u32)aliveB[1][row] & (u32)aliveB[2][row];
                        if (__ballot(comb != 0u) == 0ULL) break;
                    }
                }
                if (dead && !written) aliveB[kc][row] = 0;
            }
        } else {
            // ---- intra-segment tile of s+1 (waves 13-15, units 4/3/3)
            if (s + 1 < NSEG) {
                int g3 = w - 13;
                int nu = TILE_N[g3];
                for (int ui = 0; ui < nu; ++ui) {
                    int u = TILE_U[g3][ui];
                    int wc = u & 3, h = u >> 2;
                    int c = wc * 64 + lane;
                    float4 cb = segBox[bufn][c];
                    float  ca = segArea[bufn][c];
                    for (int r = h * 64; r < h * 64 + 64; ++r) {
                        float4 rb = segBox[bufn][r];
                        float  ra = segArea[bufn][r];
                        bool bit = (r < c) && iou_supp(rb, ra, cb, ca);
                        u64 bal = __ballot(bit);
                        if (lane == 0) tile[bufn][r][2 * wc]     = (u32)bal;
                        if (lane == 1) tile[bufn][r][2 * wc + 1] = (u32)(bal >> 32);
                    }
                }
            }
        }
        Kprev = Kcur;
    }
    __syncthreads();

    // ---- epilogue: write output
    int K = Kvar;
    for (int s2 = t; s2 < POST; s2 += 1024) {
        float* o = out + ((size_t)b * POST + s2) * 5;
        if (s2 < K) {
            float4 bx = keptBox[s2];
            o[0] = (float)b; o[1] = bx.x; o[2] = bx.y; o[3] = bx.z; o[4] = bx.w;
        } else {
            o[0] = (float)b; o[1] = 0.f; o[2] = 0.f; o[3] = 0.f; o[4] = 0.f;
        }
    }
}

// ---------------- fallback: monolithic sort+decode+NMS (small ws) --------------
__global__ __launch_bounds__(1024) void final_kernel(const u64* __restrict__ cand, const u32* __restrict__ cntp,
                             const float* __restrict__ deltas, const float* __restrict__ img_info,
                             float* __restrict__ out) {
    __shared__ union {
        u64 keys[CAP];
        struct {
            float boxes[PRE][4];
            float areas[PRE];
            u32   alive[192];
        } n;
    } sh;
    __shared__ int s_next;

    int b = blockIdx.x;
    int tid = threadIdx.x;

    for (int s = tid; s < POST; s += 1024) {
        float* o = out + ((size_t)b * POST + s) * 5;
        o[0] = (float)b; o[1] = 0.f; o[2] = 0.f; o[3] = 0.f; o[4] = 0.f;
    }

    int n = (int)min(cntp[b * 64], (u32)CAP);
    for (int i = tid; i < CAP; i += 1024)
        sh.keys[i] = (i < n) ? cand[(size_t)b * CAP + i] : 0ULL;
    __syncthreads();

    for (int k = 2; k <= CAP; k <<= 1) {
        for (int j = k >> 1; j > 0; j >>= 1) {
            for (int i = tid; i < CAP; i += 1024) {
                int ixj = i ^ j;
                if (ixj > i) {
                    u64 x = sh.keys[i], y = sh.keys[ixj];
                    bool desc = ((i & k) == 0);
                    if (desc ? (x < y) : (x > y)) { sh.keys[i] = y; sh.keys[ixj] = x; }
                }
            }
            __syncthreads();
        }
    }

    u32 myIdx[6];
    #pragma unroll
    for (int r = 0; r < 6; r++) {
        int i = tid + r * 1024;
        if (i < PRE) myIdx[r] = ~(u32)(sh.keys[i]);
    }
    __syncthreads();

    float hmax = __fsub_rn(img_info[b * 3 + 0], 1.0f);
    float wmax = __fsub_rn(img_info[b * 3 + 1], 1.0f);

    #pragma unroll
    for (int r = 0; r < 6; r++) {
        int i = tid + r * 1024;
        if (i < PRE) {
            int a = (int)myIdx[r];
            float a0, a1, a2, a3;
            anchor_at(a, a0, a1, a2, a3);
            const float4 d4 = *(const float4*)(deltas + ((size_t)b * NA + a) * 4);
            float w  = __fadd_rn(__fsub_rn(a2, a0), 1.0f);
            float h  = __fadd_rn(__fsub_rn(a3, a1), 1.0f);
            float cx = __fadd_rn(a0, __fmul_rn(0.5f, w));
            float cy = __fadd_rn(a1, __fmul_rn(0.5f, h));
            float pcx = __fadd_rn(__fmul_rn(d4.x, w), cx);
            float pcy = __fadd_rn(__fmul_rn(d4.y, h), cy);
            float pw  = __fmul_rn((float)exp((double)d4.z), w);
            float ph  = __fmul_rn((float)exp((double)d4.w), h);
            float x1 = __fsub_rn(pcx, __fmul_rn(0.5f, pw));
            float y1 = __fsub_rn(pcy, __fmul_rn(0.5f, ph));
            float x2 = __fadd_rn(pcx, __fmul_rn(0.5f, pw));
            float y2 = __fadd_rn(pcy, __fmul_rn(0.5f, ph));
            x1 = fminf(fmaxf(x1, 0.f), wmax);
            x2 = fminf(fmaxf(x2, 0.f), wmax);
            y1 = fminf(fmaxf(y1, 0.f), hmax);
            y2 = fminf(fmaxf(y2, 0.f), hmax);
            sh.n.boxes[i][0] = x1; sh.n.boxes[i][1] = y1;
            sh.n.boxes[i][2] = x2; sh.n.boxes[i][3] = y2;
            sh.n.areas[i] = __fmul_rn(__fadd_rn(__fsub_rn(x2, x1), 1.0f),
                                      __fadd_rn(__fsub_rn(y2, y1), 1.0f));
        }
    }

    for (int wdi = tid; wdi < 192; wdi += 1024) {
        u32 v = 0xFFFFFFFFu;
        if (wdi == 187) v = 0x0000FFFFu;
        if (wdi > 187)  v = 0u;
        sh.n.alive[wdi] = v;
    }
    __syncthreads();

    int kept = 0;
    int scanWord = 0;
    while (kept < POST) {
        if (tid == 0) {
            int found = -1;
            while (scanWord < 188) {
                u32 wv = sh.n.alive[scanWord];
                if (wv) { found = scanWord * 32 + (__ffs(wv) - 1); break; }
                scanWord++;
            }
            s_next = found;
        }
        __syncthreads();
        int i = s_next;
        if (i < 0) break;
        float bx1 = sh.n.boxes[i][0], by1 = sh.n.boxes[i][1];
        float bx2 = sh.n.boxes[i][2], by2 = sh.n.boxes[i][3];
        float bar = sh.n.areas[i];
        if (tid == 0) {
            float* o = out + ((size_t)b * POST + kept) * 5;
            o[1] = bx1; o[2] = by1; o[3] = bx2; o[4] = by2;
            atomicAnd(&sh.n.alive[i >> 5], ~(1u << (i & 31)));
        }
        for (int j = i + 1 + tid; j < PRE; j += 1024) {
            float x1 = sh.n.boxes[j][0], y1 = sh.n.boxes[j][1];
            float x2 = sh.n.boxes[j][2], y2 = sh.n.boxes[j][3];
            float xx1 = fmaxf(x1, bx1), yy1 = fmaxf(y1, by1);
            float xx2 = fminf(x2, bx2), yy2 = fminf(y2, by2);
            float iw = fmaxf(__fadd_rn(__fsub_rn(xx2, xx1), 1.0f), 0.f);
            float ih = fmaxf(__fadd_rn(__fsub_rn(yy2, yy1), 1.0f), 0.f);
            float inter = __fmul_rn(iw, ih);
            float denom = __fsub_rn(__fadd_rn(sh.n.areas[j], bar), inter);
            float iou = __fdiv_rn(inter, denom);
            if (iou > 0.7f) atomicAnd(&sh.n.alive[j >> 5], ~(1u << (j & 31)));
        }
        kept++;
        __syncthreads();
    }
}

// ---------------- launcher -----------------------------------------------------
extern "C" void kernel_launch(void* const* d_in, const int* in_sizes, int n_in,
                              void* d_out, int out_size, void* d_ws, size_t ws_size,
                              hipStream_t stream) {
    const float* probs    = (const float*)d_in[0];
    const float* deltas   = (const float*)d_in[1];
    const float* img_info = (const float*)d_in[2];
    float* out = (float*)d_out;

    char* ws = (char*)d_ws;
    size_t off = 0;
    u32* cntp = (u32*)(ws + off); off += (size_t)NB * 64 * sizeof(u32);
    u32* flag = (u32*)(ws + off); off += (size_t)NB * 64 * sizeof(u32);
    u32* thr  = (u32*)(ws + off); off += 4096;
    u32* hist = (u32*)(ws + off); off += (size_t)NB * 65536 * sizeof(u32);
    u64* cand = (u64*)(ws + off); off += (size_t)NB * CAP * sizeof(u64);
    float4* gBoxes = (float4*)(ws + off); off += (size_t)NB * BOXSTRIDE * sizeof(float4);
    float*  gAreas = (float*)(ws + off);  off += (size_t)NB * BOXSTRIDE * sizeof(float);
    bool bigws = (ws_size >= off);

    dim3 gA((NA + 255) / 256, NB);

    hipMemsetAsync(cntp, 0, (size_t)NB * 64 * sizeof(u32), stream);

    if (bigws) {
        compact_fixed<<<gA, 256, 0, stream>>>(probs, cntp, cand);
        check_kernel<<<1, 64, 0, stream>>>(cntp, flag);
        zero_hist<<<dim3(256, NB), 256, 0, stream>>>(flag, hist);
        hist_kernel<<<gA, 256, 0, stream>>>(flag, probs, hist);
        thresh_kernel<<<NB, 1024, 0, stream>>>(flag, hist, thr);
        compact2_kernel<<<gA, 256, 0, stream>>>(flag, probs, thr, cntp, cand);
        sort_kernel<<<NB, 1024, 0, stream>>>(cand, cntp);
        decode_all<<<dim3(BOXSTRIDE / 256, NB), 256, 0, stream>>>(cand, deltas, img_info,
                                                                  gBoxes, gAreas, out);
        nms_fused<<<NB, 1024, 0, stream>>>(gBoxes, gAreas, out);
    } else {
        hipMemsetAsync(flag, 1, (size_t)NB * 64 * sizeof(u32), stream);
        hipMemsetAsync(hist, 0, (size_t)NB * 65536 * sizeof(u32), stream);
        hist_kernel<<<gA, 256, 0, stream>>>(flag, probs, hist);
        thresh_kernel<<<NB, 1024, 0, stream>>>(flag, hist, thr);
        compact2_kernel<<<gA, 256, 0, stream>>>(flag, probs, thr, cntp, cand);
        final_kernel<<<NB, 1024, 0, stream>>>(cand, cntp, deltas, img_info, out);
    }
}